// Round 1
// baseline (3014.467 us; speedup 1.0000x reference)
//
#include <hip/hip_runtime.h>

// ---------------------------------------------------------------------------
// HoCN: deg -> dinv -> spmm(x)->h1 -> spmm(h1)->h2 -> query epilogue
// Baseline strategy: atomic-scatter SPMM (one wave per edge, float2/lane),
// float4 query epilogue. Workspace: [deg N][dinv N][h1 N*D][h2 N*D].
// ---------------------------------------------------------------------------

static constexpr int D = 128;

__global__ __launch_bounds__(256) void k_degree(const int* __restrict__ row,
                                                float* __restrict__ deg, int E) {
    int i = blockIdx.x * blockDim.x + threadIdx.x;
    if (i < E) atomicAdd(&deg[row[i]], 1.0f);
}

__global__ __launch_bounds__(256) void k_dinv(const float* __restrict__ deg,
                                              float* __restrict__ dinv, int N) {
    int i = blockIdx.x * blockDim.x + threadIdx.x;
    if (i < N) {
        float d = deg[i];
        // deg is a small non-negative integer; 1/sqrt is ~1ulp here, matches
        // the reference's rsqrt(max(deg,1e-12)) masked by deg>0.
        dinv[i] = (d > 0.0f) ? (1.0f / sqrtf(d)) : 0.0f;
    }
}

// One 64-lane wave per edge; each lane handles 2 features (float2).
// out[row] += dinv[row]*dinv[col] * feat[col]
__global__ __launch_bounds__(256) void k_spmm(const int* __restrict__ row,
                                              const int* __restrict__ col,
                                              const float* __restrict__ dinv,
                                              const float* __restrict__ feat,
                                              float* __restrict__ out, int E) {
    int e = blockIdx.x * 4 + (threadIdx.x >> 6);
    if (e >= E) return;
    int lane = threadIdx.x & 63;
    int r = row[e];
    int c = col[e];
    float w = dinv[r] * dinv[c];
    float2 xv = ((const float2*)(feat + (size_t)c * D))[lane];
    float* o = out + (size_t)r * D + lane * 2;
    atomicAdd(o, w * xv.x);
    atomicAdd(o + 1, w * xv.y);
}

__device__ __forceinline__ float4 f4mul(float4 a, float4 b) {
    return make_float4(a.x * b.x, a.y * b.y, a.z * b.z, a.w * b.w);
}
// b - s*a, componentwise
__device__ __forceinline__ float4 f4subs(float4 b, float s, float4 a) {
    return make_float4(b.x - s * a.x, b.y - s * a.y, b.z - s * a.z, b.w - s * a.w);
}

// One 32-lane group per query; each lane handles 4 features (float4).
__global__ __launch_bounds__(256) void k_query(const int* __restrict__ U,
                                               const int* __restrict__ V,
                                               const float* __restrict__ x,
                                               const float* __restrict__ h1,
                                               const float* __restrict__ h2,
                                               const float* __restrict__ deg,
                                               float* __restrict__ out, int Q) {
    int t = blockIdx.x * blockDim.x + threadIdx.x;
    int q = t >> 5;
    if (q >= Q) return;
    int lane = t & 31;
    int u = U[q];
    int v = V[q];
    float du = deg[u];
    float dv = deg[v];

    const float4* xf  = (const float4*)x;
    const float4* h1f = (const float4*)h1;
    const float4* h2f = (const float4*)h2;
    size_t ub = (size_t)u * (D / 4) + lane;
    size_t vb = (size_t)v * (D / 4) + lane;

    float4 xu  = xf[ub],  xv  = xf[vb];
    float4 a1u = h1f[ub], a1v = h1f[vb];
    float4 a2u = h2f[ub], a2v = h2f[vb];

    size_t QD4 = (size_t)Q * (D / 4);
    size_t qb  = (size_t)q * (D / 4) + lane;
    float4* of = (float4*)out;

    of[0 * QD4 + qb] = f4mul(a1u, a1v);                                   // count_1_1
    of[1 * QD4 + qb] = f4mul(a1u, a2v);                                   // count_1_2
    of[2 * QD4 + qb] = f4mul(a2u, a1v);                                   // count_2_1
    of[3 * QD4 + qb] = f4mul(f4subs(a2u, du, xu), f4subs(a2v, dv, xv));   // count_2_2
    of[4 * QD4 + qb] = f4mul(a1u, a2u);                                   // count_self_1_2
    of[5 * QD4 + qb] = f4mul(a1v, a2v);                                   // count_self_2_1

    if (lane == 0) {
        float* tail = out + 6 * (size_t)Q * D;
        tail[q]     = du;   // deg_u
        tail[Q + q] = dv;   // deg_v
    }
}

extern "C" void kernel_launch(void* const* d_in, const int* in_sizes, int n_in,
                              void* d_out, int out_size, void* d_ws, size_t ws_size,
                              hipStream_t stream) {
    const float* x     = (const float*)d_in[0];
    const int*   edges = (const int*)d_in[1];
    const int*   eidx  = (const int*)d_in[2];

    const int N = in_sizes[0] / D;   // 50000
    const int Q = in_sizes[1] / 2;   // 100000
    const int E = in_sizes[2] / 2;   // 1600000

    const int* U   = edges;
    const int* V   = edges + Q;
    const int* row = eidx;
    const int* col = eidx + E;

    float* deg  = (float*)d_ws;
    float* dinv = deg + N;
    float* h1   = dinv + N;
    float* h2   = h1 + (size_t)N * D;

    // Zero deg + dinv + h1 + h2 (workspace is re-poisoned 0xAA every call).
    size_t zero_bytes = ((size_t)2 * N + 2 * (size_t)N * D) * sizeof(float);
    hipMemsetAsync(d_ws, 0, zero_bytes, stream);

    float* out = (float*)d_out;

    k_degree<<<(E + 255) / 256, 256, 0, stream>>>(row, deg, E);
    k_dinv<<<(N + 255) / 256, 256, 0, stream>>>(deg, dinv, N);
    k_spmm<<<(E + 3) / 4, 256, 0, stream>>>(row, col, dinv, x, h1, E);
    k_spmm<<<(E + 3) / 4, 256, 0, stream>>>(row, col, dinv, h1, h2, E);
    k_query<<<(Q + 7) / 8, 256, 0, stream>>>(U, V, x, h1, h2, deg, out, Q);
}

// Round 2
// 873.606 us; speedup vs baseline: 3.4506x; 3.4506x over previous
//
#include <hip/hip_runtime.h>

// ---------------------------------------------------------------------------
// HoCN round 2: CSR-gather SPMM (no feature atomics).
// Pipeline: memset(degi,cursor) -> k_degree(int atomics) -> k_scan(rowptr)
//           -> k_degdinv -> k_scatter(csr_col,csr_val) -> spmm(x)->h1
//           -> spmm(h1)->h2 -> k_query.
// SPMM: one 64-lane wave per row; lane owns float2 of the 128 features;
// neighbor (col,val) loaded 64-wide and broadcast via __shfl.
// ---------------------------------------------------------------------------

static constexpr int D = 128;

__global__ __launch_bounds__(256) void k_degree(const int* __restrict__ row,
                                                int* __restrict__ degi, int E) {
    int i = blockIdx.x * blockDim.x + threadIdx.x;
    if (i < E) atomicAdd(&degi[row[i]], 1);
}

// Single-block exclusive scan: rowptr[0]=0, rowptr[i+1]=sum(degi[0..i]).
__global__ __launch_bounds__(1024) void k_scan(const int* __restrict__ degi,
                                               int* __restrict__ rowptr, int N) {
    __shared__ int buf[1024];
    __shared__ int carry;
    int t = threadIdx.x;
    if (t == 0) { carry = 0; rowptr[0] = 0; }
    __syncthreads();
    for (int base = 0; base < N; base += 1024) {
        int i = base + t;
        int v = (i < N) ? degi[i] : 0;
        buf[t] = v;
        __syncthreads();
        for (int off = 1; off < 1024; off <<= 1) {
            int add = (t >= off) ? buf[t - off] : 0;
            __syncthreads();
            buf[t] += add;
            __syncthreads();
        }
        if (i < N) rowptr[i + 1] = buf[t] + carry;
        __syncthreads();
        if (t == 0) carry += buf[1023];
        __syncthreads();
    }
}

__global__ __launch_bounds__(256) void k_degdinv(const int* __restrict__ degi,
                                                 float* __restrict__ deg,
                                                 float* __restrict__ dinv, int N) {
    int i = blockIdx.x * blockDim.x + threadIdx.x;
    if (i < N) {
        float d = (float)degi[i];
        deg[i] = d;
        dinv[i] = (d > 0.0f) ? (1.0f / sqrtf(d)) : 0.0f;
    }
}

__global__ __launch_bounds__(256) void k_scatter(const int* __restrict__ row,
                                                 const int* __restrict__ col,
                                                 const int* __restrict__ rowptr,
                                                 int* __restrict__ cursor,
                                                 const float* __restrict__ dinv,
                                                 int* __restrict__ csr_col,
                                                 float* __restrict__ csr_val, int E) {
    int e = blockIdx.x * blockDim.x + threadIdx.x;
    if (e < E) {
        int r = row[e];
        int c = col[e];
        int pos = atomicAdd(&cursor[r], 1);
        int idx = rowptr[r] + pos;
        csr_col[idx] = c;
        csr_val[idx] = dinv[r] * dinv[c];
    }
}

// One wave per row; lane owns features [2*lane, 2*lane+1].
__global__ __launch_bounds__(256) void k_spmm_csr(const int* __restrict__ rowptr,
                                                  const int* __restrict__ csr_col,
                                                  const float* __restrict__ csr_val,
                                                  const float* __restrict__ feat,
                                                  float* __restrict__ out, int N) {
    int r = blockIdx.x * 4 + (threadIdx.x >> 6);
    if (r >= N) return;
    int lane = threadIdx.x & 63;
    int beg = rowptr[r];
    int end = rowptr[r + 1];
    float accx = 0.0f, accy = 0.0f;
    for (int j0 = beg; j0 < end; j0 += 64) {
        int navail = end - j0;
        int jj = j0 + lane;
        int cg = (lane < navail) ? csr_col[jj] : 0;
        float wg = (lane < navail) ? csr_val[jj] : 0.0f;
        int m = navail < 64 ? navail : 64;
        for (int k = 0; k < m; ++k) {
            int ck = __shfl(cg, k);
            float wk = __shfl(wg, k);
            float2 xv = ((const float2*)(feat + (size_t)ck * D))[lane];
            accx = fmaf(wk, xv.x, accx);
            accy = fmaf(wk, xv.y, accy);
        }
    }
    float2 o;
    o.x = accx; o.y = accy;
    ((float2*)(out + (size_t)r * D))[lane] = o;
}

__device__ __forceinline__ float4 f4mul(float4 a, float4 b) {
    return make_float4(a.x * b.x, a.y * b.y, a.z * b.z, a.w * b.w);
}
__device__ __forceinline__ float4 f4subs(float4 b, float s, float4 a) {
    return make_float4(b.x - s * a.x, b.y - s * a.y, b.z - s * a.z, b.w - s * a.w);
}

// One 32-lane group per query; each lane handles 4 features (float4).
__global__ __launch_bounds__(256) void k_query(const int* __restrict__ U,
                                               const int* __restrict__ V,
                                               const float* __restrict__ x,
                                               const float* __restrict__ h1,
                                               const float* __restrict__ h2,
                                               const float* __restrict__ deg,
                                               float* __restrict__ out, int Q) {
    int t = blockIdx.x * blockDim.x + threadIdx.x;
    int q = t >> 5;
    if (q >= Q) return;
    int lane = t & 31;
    int u = U[q];
    int v = V[q];
    float du = deg[u];
    float dv = deg[v];

    const float4* xf  = (const float4*)x;
    const float4* h1f = (const float4*)h1;
    const float4* h2f = (const float4*)h2;
    size_t ub = (size_t)u * (D / 4) + lane;
    size_t vb = (size_t)v * (D / 4) + lane;

    float4 xu  = xf[ub],  xv  = xf[vb];
    float4 a1u = h1f[ub], a1v = h1f[vb];
    float4 a2u = h2f[ub], a2v = h2f[vb];

    size_t QD4 = (size_t)Q * (D / 4);
    size_t qb  = (size_t)q * (D / 4) + lane;
    float4* of = (float4*)out;

    of[0 * QD4 + qb] = f4mul(a1u, a1v);
    of[1 * QD4 + qb] = f4mul(a1u, a2v);
    of[2 * QD4 + qb] = f4mul(a2u, a1v);
    of[3 * QD4 + qb] = f4mul(f4subs(a2u, du, xu), f4subs(a2v, dv, xv));
    of[4 * QD4 + qb] = f4mul(a1u, a2u);
    of[5 * QD4 + qb] = f4mul(a1v, a2v);

    if (lane == 0) {
        float* tail = out + 6 * (size_t)Q * D;
        tail[q]     = du;
        tail[Q + q] = dv;
    }
}

extern "C" void kernel_launch(void* const* d_in, const int* in_sizes, int n_in,
                              void* d_out, int out_size, void* d_ws, size_t ws_size,
                              hipStream_t stream) {
    const float* x     = (const float*)d_in[0];
    const int*   edges = (const int*)d_in[1];
    const int*   eidx  = (const int*)d_in[2];

    const int N = in_sizes[0] / D;   // 50000
    const int Q = in_sizes[1] / 2;   // 100000
    const int E = in_sizes[2] / 2;   // 1600000

    const int* U   = edges;
    const int* V   = edges + Q;
    const int* row = eidx;
    const int* col = eidx + E;

    // Workspace layout (all 4-byte elements; keep h1 16B-aligned).
    int Npad = ((N + 1 + 3) / 4) * 4;  // rowptr padded
    int*   degi    = (int*)d_ws;
    int*   cursor  = degi + N;
    int*   rowptr  = cursor + N;
    float* deg     = (float*)(rowptr + Npad);
    float* dinv    = deg + N;
    int*   csr_col = (int*)(dinv + N);
    float* csr_val = (float*)(csr_col + E);
    float* h1      = csr_val + E;
    float* h2      = h1 + (size_t)N * D;

    // Zero degi + cursor (contiguous). h1/h2 are fully overwritten by SPMM.
    hipMemsetAsync(degi, 0, (size_t)2 * N * sizeof(int), stream);

    float* out = (float*)d_out;

    k_degree<<<(E + 255) / 256, 256, 0, stream>>>(row, degi, E);
    k_scan<<<1, 1024, 0, stream>>>(degi, rowptr, N);
    k_degdinv<<<(N + 255) / 256, 256, 0, stream>>>(degi, deg, dinv, N);
    k_scatter<<<(E + 255) / 256, 256, 0, stream>>>(row, col, rowptr, cursor, dinv,
                                                   csr_col, csr_val, E);
    k_spmm_csr<<<(N + 3) / 4, 256, 0, stream>>>(rowptr, csr_col, csr_val, x, h1, N);
    k_spmm_csr<<<(N + 3) / 4, 256, 0, stream>>>(rowptr, csr_col, csr_val, h1, h2, N);
    k_query<<<(Q + 7) / 8, 256, 0, stream>>>(U, V, x, h1, h2, deg, out, Q);
}

// Round 3
// 742.747 us; speedup vs baseline: 4.0585x; 1.1762x over previous
//
#include <hip/hip_runtime.h>

// ---------------------------------------------------------------------------
// HoCN round 3:
//  - hierarchical 3-stage scan (was: single-block 1024-thread scan, ~1000
//    barriers on one CU)
//  - CSR packed as int2 {col, weight bits}: one dwordx2 per edge
//  - SPMM inner broadcast loop unrolled x4: 4 independent 512B gathers in
//    flight per wave
// Pipeline: memset(degi) -> k_degree -> scan1/scan2/scan3(fused dinv+cursor)
//           -> k_scatter -> spmm(x)->h1 -> spmm(h1)->h2 -> k_query
// ---------------------------------------------------------------------------

static constexpr int D = 128;
static constexpr int SCAN_B = 256;

__global__ __launch_bounds__(256) void k_degree(const int* __restrict__ row,
                                                int* __restrict__ degi, int E) {
    int i = blockIdx.x * blockDim.x + threadIdx.x;
    if (i < E) atomicAdd(&degi[row[i]], 1);
}

// Stage 1: per-block inclusive scan; write inclusive partials + block sum.
__global__ __launch_bounds__(SCAN_B) void k_scan1(const int* __restrict__ degi,
                                                  int* __restrict__ part,
                                                  int* __restrict__ bsum, int N) {
    __shared__ int buf[SCAN_B];
    int t = threadIdx.x;
    int i = blockIdx.x * SCAN_B + t;
    int v = (i < N) ? degi[i] : 0;
    buf[t] = v;
    __syncthreads();
    for (int off = 1; off < SCAN_B; off <<= 1) {
        int a = (t >= off) ? buf[t - off] : 0;
        __syncthreads();
        buf[t] += a;
        __syncthreads();
    }
    if (i < N) part[i] = buf[t];
    if (t == SCAN_B - 1) bsum[blockIdx.x] = buf[t];
}

// Stage 2: single-block exclusive scan of block sums (generic over nb).
__global__ __launch_bounds__(SCAN_B) void k_scan2(int* __restrict__ bsum, int nb) {
    __shared__ int buf[SCAN_B];
    __shared__ int carry;
    int t = threadIdx.x;
    if (t == 0) carry = 0;
    __syncthreads();
    for (int base = 0; base < nb; base += SCAN_B) {
        int i = base + t;
        int v = (i < nb) ? bsum[i] : 0;
        buf[t] = v;
        __syncthreads();
        for (int off = 1; off < SCAN_B; off <<= 1) {
            int a = (t >= off) ? buf[t - off] : 0;
            __syncthreads();
            buf[t] += a;
            __syncthreads();
        }
        if (i < nb) bsum[i] = buf[t] - v + carry;  // exclusive + carry
        __syncthreads();
        if (t == 0) carry += buf[SCAN_B - 1];
        __syncthreads();
    }
}

// Stage 3: rowptr = part + block offset; fused deg/dinv/cursor init.
__global__ __launch_bounds__(256) void k_scan3(const int* __restrict__ part,
                                               const int* __restrict__ bsum,
                                               const int* __restrict__ degi,
                                               int* __restrict__ rowptr,
                                               int* __restrict__ cursor,
                                               float* __restrict__ deg,
                                               float* __restrict__ dinv, int N) {
    int i = blockIdx.x * blockDim.x + threadIdx.x;
    if (i < N) {
        rowptr[i + 1] = part[i] + bsum[i >> 8];
        if (i == 0) rowptr[0] = 0;
        cursor[i] = 0;
        float d = (float)degi[i];
        deg[i] = d;
        dinv[i] = (d > 0.0f) ? (1.0f / sqrtf(d)) : 0.0f;
    }
}

__global__ __launch_bounds__(256) void k_scatter(const int* __restrict__ row,
                                                 const int* __restrict__ col,
                                                 const int* __restrict__ rowptr,
                                                 int* __restrict__ cursor,
                                                 const float* __restrict__ dinv,
                                                 int2* __restrict__ csr, int E) {
    int e = blockIdx.x * blockDim.x + threadIdx.x;
    if (e < E) {
        int r = row[e];
        int c = col[e];
        int pos = atomicAdd(&cursor[r], 1);
        int idx = rowptr[r] + pos;
        int2 cw;
        cw.x = c;
        cw.y = __float_as_int(dinv[r] * dinv[c]);
        csr[idx] = cw;
    }
}

// One wave per row; lane owns features [2*lane, 2*lane+1]. Inner broadcast
// loop unrolled x4 so 4 independent 512B feature-row gathers are in flight.
__global__ __launch_bounds__(256) void k_spmm_csr(const int* __restrict__ rowptr,
                                                  const int2* __restrict__ csr,
                                                  const float* __restrict__ feat,
                                                  float* __restrict__ out, int N) {
    int r = blockIdx.x * 4 + (threadIdx.x >> 6);
    if (r >= N) return;
    int lane = threadIdx.x & 63;
    int beg = rowptr[r];
    int end = rowptr[r + 1];
    const float2* f2 = (const float2*)feat;
    float accx = 0.0f, accy = 0.0f;
    for (int j0 = beg; j0 < end; j0 += 64) {
        int m = end - j0;
        if (m > 64) m = 64;
        int2 cw = (lane < m) ? csr[j0 + lane] : make_int2(0, 0);
        int k = 0;
        for (; k + 4 <= m; k += 4) {
            int c0 = __shfl(cw.x, k);
            int c1 = __shfl(cw.x, k + 1);
            int c2 = __shfl(cw.x, k + 2);
            int c3 = __shfl(cw.x, k + 3);
            float w0 = __int_as_float(__shfl(cw.y, k));
            float w1 = __int_as_float(__shfl(cw.y, k + 1));
            float w2 = __int_as_float(__shfl(cw.y, k + 2));
            float w3 = __int_as_float(__shfl(cw.y, k + 3));
            float2 x0 = f2[(size_t)c0 * 64 + lane];
            float2 x1 = f2[(size_t)c1 * 64 + lane];
            float2 x2 = f2[(size_t)c2 * 64 + lane];
            float2 x3 = f2[(size_t)c3 * 64 + lane];
            accx = fmaf(w0, x0.x, accx); accy = fmaf(w0, x0.y, accy);
            accx = fmaf(w1, x1.x, accx); accy = fmaf(w1, x1.y, accy);
            accx = fmaf(w2, x2.x, accx); accy = fmaf(w2, x2.y, accy);
            accx = fmaf(w3, x3.x, accx); accy = fmaf(w3, x3.y, accy);
        }
        for (; k < m; ++k) {
            int ck = __shfl(cw.x, k);
            float wk = __int_as_float(__shfl(cw.y, k));
            float2 xv = f2[(size_t)ck * 64 + lane];
            accx = fmaf(wk, xv.x, accx);
            accy = fmaf(wk, xv.y, accy);
        }
    }
    float2 o;
    o.x = accx; o.y = accy;
    ((float2*)out)[(size_t)r * 64 + lane] = o;
}

__device__ __forceinline__ float4 f4mul(float4 a, float4 b) {
    return make_float4(a.x * b.x, a.y * b.y, a.z * b.z, a.w * b.w);
}
__device__ __forceinline__ float4 f4subs(float4 b, float s, float4 a) {
    return make_float4(b.x - s * a.x, b.y - s * a.y, b.z - s * a.z, b.w - s * a.w);
}

// One 32-lane group per query; each lane handles 4 features (float4).
__global__ __launch_bounds__(256) void k_query(const int* __restrict__ U,
                                               const int* __restrict__ V,
                                               const float* __restrict__ x,
                                               const float* __restrict__ h1,
                                               const float* __restrict__ h2,
                                               const float* __restrict__ deg,
                                               float* __restrict__ out, int Q) {
    int t = blockIdx.x * blockDim.x + threadIdx.x;
    int q = t >> 5;
    if (q >= Q) return;
    int lane = t & 31;
    int u = U[q];
    int v = V[q];
    float du = deg[u];
    float dv = deg[v];

    const float4* xf  = (const float4*)x;
    const float4* h1f = (const float4*)h1;
    const float4* h2f = (const float4*)h2;
    size_t ub = (size_t)u * (D / 4) + lane;
    size_t vb = (size_t)v * (D / 4) + lane;

    float4 xu  = xf[ub],  xv  = xf[vb];
    float4 a1u = h1f[ub], a1v = h1f[vb];
    float4 a2u = h2f[ub], a2v = h2f[vb];

    size_t QD4 = (size_t)Q * (D / 4);
    size_t qb  = (size_t)q * (D / 4) + lane;
    float4* of = (float4*)out;

    of[0 * QD4 + qb] = f4mul(a1u, a1v);
    of[1 * QD4 + qb] = f4mul(a1u, a2v);
    of[2 * QD4 + qb] = f4mul(a2u, a1v);
    of[3 * QD4 + qb] = f4mul(f4subs(a2u, du, xu), f4subs(a2v, dv, xv));
    of[4 * QD4 + qb] = f4mul(a1u, a2u);
    of[5 * QD4 + qb] = f4mul(a1v, a2v);

    if (lane == 0) {
        float* tail = out + 6 * (size_t)Q * D;
        tail[q]     = du;
        tail[Q + q] = dv;
    }
}

extern "C" void kernel_launch(void* const* d_in, const int* in_sizes, int n_in,
                              void* d_out, int out_size, void* d_ws, size_t ws_size,
                              hipStream_t stream) {
    const float* x     = (const float*)d_in[0];
    const int*   edges = (const int*)d_in[1];
    const int*   eidx  = (const int*)d_in[2];

    const int N = in_sizes[0] / D;   // 50000
    const int Q = in_sizes[1] / 2;   // 100000
    const int E = in_sizes[2] / 2;   // 1600000

    const int* U   = edges;
    const int* V   = edges + Q;
    const int* row = eidx;
    const int* col = eidx + E;

    const int nb = (N + SCAN_B - 1) / SCAN_B;   // scan blocks

    // Workspace layout (keep 8/16B alignment for csr/h1).
    int Npad = ((N + 1 + 3) / 4) * 4;
    int nbpad = ((nb + 3) / 4) * 4;
    int*   degi   = (int*)d_ws;
    int*   part   = degi + N;
    int*   bsum   = part + N;
    int*   rowptr = bsum + nbpad;
    int*   cursor = rowptr + Npad;
    float* deg    = (float*)(cursor + N);
    float* dinv   = deg + N;
    int2*  csr    = (int2*)(dinv + N);          // 8B-aligned (offset is even #ints)
    float* h1     = (float*)(csr + E);
    float* h2     = h1 + (size_t)N * D;

    hipMemsetAsync(degi, 0, (size_t)N * sizeof(int), stream);

    float* out = (float*)d_out;

    k_degree<<<(E + 255) / 256, 256, 0, stream>>>(row, degi, E);
    k_scan1<<<nb, SCAN_B, 0, stream>>>(degi, part, bsum, N);
    k_scan2<<<1, SCAN_B, 0, stream>>>(bsum, nb);
    k_scan3<<<(N + 255) / 256, 256, 0, stream>>>(part, bsum, degi, rowptr, cursor,
                                                 deg, dinv, N);
    k_scatter<<<(E + 255) / 256, 256, 0, stream>>>(row, col, rowptr, cursor, dinv,
                                                   csr, E);
    k_spmm_csr<<<(N + 3) / 4, 256, 0, stream>>>(rowptr, csr, x, h1, N);
    k_spmm_csr<<<(N + 3) / 4, 256, 0, stream>>>(rowptr, csr, h1, h2, N);
    k_query<<<(Q + 7) / 8, 256, 0, stream>>>(U, V, x, h1, h2, deg, out, Q);
}